// Round 8
// baseline (309.954 us; speedup 1.0000x reference)
//
#include <hip/hip_runtime.h>
#include <hip/hip_bf16.h>
#include <stdint.h>

#define Bb 32
#define Tt 2048
#define Dd 1024   // D_IN = D_H = D_OUT

typedef float    f32x4 __attribute__((ext_vector_type(4)));
typedef _Float16 f16x8 __attribute__((ext_vector_type(8)));
typedef uint32_t u32;

// ---- ws layout (bytes) ----
// 0        w2_ws [32][1024] f32  (2 * s.W_a)     128K
// 131072   e_ws  [32][2048] f32                  256K
// 393216   a_ws  [32][2048] f32                  256K
// 655360   cpart [32 tc][32 b][1024] f32         4M
// 4849664  U_ts  chunk-major fp16 U^T (linear-lane chunks, see k_ut)  2M
#define WS_E     131072
#define WS_A     393216
#define WS_CP    655360
#define WS_UT    4849664

__device__ __forceinline__ void gll16(const void* g, const void* lds) {
  __builtin_amdgcn_global_load_lds(
      (const __attribute__((address_space(1))) u32*)(uintptr_t)g,
      (__attribute__((address_space(3))) u32*)(uint32_t)(uintptr_t)lds,
      16, 0, 0);
}

// ---------------- kernel 1: w2[b][o] = 2 * sum_i s[b][i] * W[i][o] ----------------
__global__ __launch_bounds__(256) void k_ws(const float* __restrict__ s,
                                            const float* __restrict__ W,
                                            float* __restrict__ w2_ws) {
  const int b = blockIdx.x >> 2;
  const int o = (blockIdx.x & 3) * 256 + threadIdx.x;
  __shared__ float s_sh[Dd];
#pragma unroll
  for (int j = 0; j < 4; ++j)
    s_sh[threadIdx.x + 256 * j] = s[b * Dd + threadIdx.x + 256 * j];
  __syncthreads();
  float acc = 0.f;
#pragma unroll 8
  for (int i = 0; i < Dd; ++i) acc += s_sh[i] * W[(size_t)i * Dd + o];
  w2_ws[b * Dd + o] = 2.f * acc;
}

// ------- kernel 2: build U_ts in linear-lane chunk layout -------
// chunk c (o-block c>>2, k-window (c&3)*256) = 16KB as [kk 0..7][o-half][lane][16B]:
// element (o,k): c=(o>>5)*4+(k>>8); kk=(k>>5)&7; half=(o>>4)&1; lane=((k>>3)&3)*16+(o&15).
__global__ __launch_bounds__(256) void k_ut(const float* __restrict__ U,
                                            uint8_t* __restrict__ U_ts) {
  const int i0 = (blockIdx.x >> 4) * 64;   // k-tile
  const int o0 = (blockIdx.x & 15) * 64;   // o-tile
  __shared__ float tile[64][65];           // [o_loc][k_loc]
  const int tx = threadIdx.x & 63;
  const int ty = threadIdx.x >> 6;
#pragma unroll
  for (int jj = 0; jj < 16; ++jj)
    tile[tx][ty + 4 * jj] = U[(size_t)(i0 + ty + 4 * jj) * Dd + o0 + tx];
  __syncthreads();
#pragma unroll
  for (int it = 0; it < 2; ++it) {
    const int g = it * 256 + threadIdx.x;  // 0..511
    const int o_loc = g & 63;
    const int kg = g >> 6;                 // 0..7
    const int o = o0 + o_loc;
    const int k = i0 + kg * 8;
    f16x8 r;
#pragma unroll
    for (int m = 0; m < 8; ++m) r[m] = (_Float16)tile[o_loc][kg * 8 + m];
    const int c    = (o >> 5) * 4 + (k >> 8);
    const int kk   = (k >> 5) & 7;
    const int half = (o >> 4) & 1;
    const int ln   = ((k >> 3) & 3) * 16 + (o & 15);
    *(f16x8*)(U_ts + (size_t)c * 16384 + kk * 2048 + half * 1024 + ln * 16) = r;
  }
}

// ---------------- kernel 3: fused  e[b][t] = sum_o v_o * tanh(w + h.U) ----------------
// 512 threads, 8 waves: th = w>>2 (32-t half), kq = w&3 (K-quarter). hreg = 64 VGPR.
// Per ot: 4 chunk phases (each wave does its K-quarter), then 2-round acc butterfly
// (R1 by o-half with kq^1, R2 by t-tile with kq^2), tanh split 4-ways.
__global__ __launch_bounds__(512, 4) void k_e(const float* __restrict__ h,
                                              const uint8_t* __restrict__ U_ts,
                                              const float* __restrict__ w2_ws,
                                              const float* __restrict__ v_a,
                                              float* __restrict__ e_ws) {
  const int b    = blockIdx.x >> 5;
  const int t0   = (blockIdx.x & 31) << 6;   // 64 t per block
  const int tid  = threadIdx.x;
  const int lane = tid & 63;
  const int w    = tid >> 6;   // 0..7
  const int th   = w >> 2;     // t-half
  const int kq   = w & 3;      // K-quarter

  __shared__ __align__(16) uint8_t ubuf[2][16384];  // chunk double-buffer
  __shared__ __align__(16) float   exchA[4096];     // 16KB (R1)
  __shared__ __align__(16) float   exchB[2048];     // 8KB  (R2 + final)
  __shared__ float w_sh[Dd];
  __shared__ float v_sh[Dd];

#pragma unroll
  for (int j = 0; j < 2; ++j) {
    const int o = tid + 512 * j;
    w_sh[o] = w2_ws[b * Dd + o];
    v_sh[o] = v_a[o];
  }

  // B-operand: 32 t-cols, this wave's K-quarter, in registers (64 VGPR).
  // hreg[(kc*2+kkl)*2+tc]; k = kc*256 + kq*64 + kkl*32 + (lane>>4)*8 + j
  f16x8 hreg[16];
  {
    const int lr = lane & 15, lg = (lane >> 4) * 8;
#pragma unroll
    for (int kc = 0; kc < 4; ++kc)
#pragma unroll
      for (int kkl = 0; kkl < 2; ++kkl)
#pragma unroll
        for (int tc = 0; tc < 2; ++tc) {
          const int trow = t0 + th * 32 + tc * 16 + lr;
          const int k = kc * 256 + kq * 64 + kkl * 32 + lg;
          const float* p = h + ((size_t)b * Tt + trow) * Dd + k;
          const f32x4 p0 = *(const f32x4*)p;
          const f32x4 p1 = *(const f32x4*)(p + 4);
          f16x8 r;
          r[0] = (_Float16)p0[0]; r[1] = (_Float16)p0[1];
          r[2] = (_Float16)p0[2]; r[3] = (_Float16)p0[3];
          r[4] = (_Float16)p1[0]; r[5] = (_Float16)p1[1];
          r[6] = (_Float16)p1[2]; r[7] = (_Float16)p1[3];
          hreg[(kc * 2 + kkl) * 2 + tc] = r;
        }
  }
  asm volatile("s_waitcnt lgkmcnt(0)" ::: "memory");  // w_sh/v_sh writes visible at 1st barrier

  // stage chunk c: 16 x 1KB segments; wave w stages segments 2w, 2w+1
  auto stage = [&](int c, int buf) {
    const uint8_t* src = U_ts + (size_t)c * 16384 + (size_t)(2 * w) * 1024 + (size_t)lane * 16;
    gll16(src,        &ubuf[buf][(2 * w) * 1024]);
    gll16(src + 1024, &ubuf[buf][(2 * w + 1) * 1024]);
  };

  stage(0, 0);

  float ep = 0.f;
  const int keepH = kq & 1;
  const int keepT = (kq >> 1) & 1;

  for (int ot = 0; ot < 32; ++ot) {
    f32x4 acc00 = {0.f,0.f,0.f,0.f};  // [o-half 0][tc0]
    f32x4 acc01 = {0.f,0.f,0.f,0.f};  // [o-half 0][tc1]
    f32x4 acc10 = {0.f,0.f,0.f,0.f};  // [o-half 1][tc0]
    f32x4 acc11 = {0.f,0.f,0.f,0.f};  // [o-half 1][tc1]
#pragma unroll
    for (int kc = 0; kc < 4; ++kc) {
      const int c = ot * 4 + kc;
      asm volatile("s_waitcnt vmcnt(0)" ::: "memory");  // my chunk-c segs (issued prev phase) done
      __builtin_amdgcn_sched_barrier(0);
      __builtin_amdgcn_s_barrier();                     // everyone's segs done
      __builtin_amdgcn_sched_barrier(0);
      const int cur = c & 1;
      if (c + 1 < 128) stage(c + 1, cur ^ 1);           // buf cur^1 free since prev barrier
      const uint8_t* ub = &ubuf[cur][(kq * 2) * 2048] + lane * 16;
      __builtin_amdgcn_s_setprio(1);
#pragma unroll
      for (int kkl = 0; kkl < 2; ++kkl) {
        const f16x8 a0 = *(const f16x8*)(ub + kkl * 2048);          // o-half 0
        const f16x8 a1 = *(const f16x8*)(ub + kkl * 2048 + 1024);   // o-half 1
        const f16x8 b0 = hreg[(kc * 2 + kkl) * 2];
        const f16x8 b1 = hreg[(kc * 2 + kkl) * 2 + 1];
        acc00 = __builtin_amdgcn_mfma_f32_16x16x32_f16(a0, b0, acc00, 0, 0, 0);
        acc01 = __builtin_amdgcn_mfma_f32_16x16x32_f16(a0, b1, acc01, 0, 0, 0);
        acc10 = __builtin_amdgcn_mfma_f32_16x16x32_f16(a1, b0, acc10, 0, 0, 0);
        acc11 = __builtin_amdgcn_mfma_f32_16x16x32_f16(a1, b1, acc11, 0, 0, 0);
      }
      __builtin_amdgcn_s_setprio(0);
    }
    // R1 with kq^1: keep o-half keepH, send the other (named vars, no runtime idx)
    {
      float* snd = exchA + w * 512 + lane * 4;
      *(f32x4*)snd         = keepH ? acc00 : acc10;
      *(f32x4*)(snd + 256) = keepH ? acc01 : acc11;
    }
    asm volatile("s_waitcnt lgkmcnt(0)" ::: "memory");
    __builtin_amdgcn_sched_barrier(0);
    __builtin_amdgcn_s_barrier();
    __builtin_amdgcn_sched_barrier(0);
    f32x4 k0, k1;
    {
      const float* rcv = exchA + (w ^ 1) * 512 + lane * 4;
      k0 = (keepH ? acc10 : acc00) + *(const f32x4*)rcv;        // kept half, tc0
      k1 = (keepH ? acc11 : acc01) + *(const f32x4*)(rcv + 256); // kept half, tc1
    }
    // R2 with kq^2: keep tc keepT, send the other
    {
      float* snd = exchB + w * 256 + lane * 4;
      *(f32x4*)snd = keepT ? k0 : k1;
    }
    asm volatile("s_waitcnt lgkmcnt(0)" ::: "memory");
    __builtin_amdgcn_sched_barrier(0);
    __builtin_amdgcn_s_barrier();
    __builtin_amdgcn_sched_barrier(0);
    f32x4 xf;
    {
      const float* rcv = exchB + (w ^ 2) * 256 + lane * 4;
      xf = (keepT ? k1 : k0) + *(const f32x4*)rcv;   // full-K sum, my (o-half, t-tile)
    }
    const int ob = ot * 32 + keepH * 16 + ((lane >> 4) << 2);
    const f32x4 w4 = *(const f32x4*)(w_sh + ob);
    const f32x4 v4 = *(const f32x4*)(v_sh + ob);
#pragma unroll
    for (int r = 0; r < 4; ++r) {
      const float e0 = __expf(__builtin_fmaf(xf[r], 2.f, w4[r]));  // exp(2*acc + 2*w)
      ep += v4[r] * (1.f - 2.f / (e0 + 1.f));                      // v * tanh
    }
    // exchA/exchB reuse next ot is ≥4 barriers away
  }

  // sum the 4 lane-groups (o rows), then combine o-half partners (kq^1) via LDS
  ep += __shfl_xor(ep, 16, 64);
  ep += __shfl_xor(ep, 32, 64);
  __syncthreads();
  if ((kq & 1) && lane < 16) exchB[(th * 2 + keepT) * 16 + lane] = ep;
  __syncthreads();
  if (!(kq & 1) && lane < 16)
    e_ws[b * Tt + t0 + th * 32 + keepT * 16 + lane] =
        ep + exchB[(th * 2 + keepT) * 16 + lane];
}

// ---------------- kernel 4: softmax over T per b ----------------
__global__ __launch_bounds__(256) void k_sm(const float* __restrict__ e_ws,
                                            float* __restrict__ a_ws) {
  const int b = blockIdx.x;
  const int lane = threadIdx.x & 63;
  const int wv = threadIdx.x >> 6;
  __shared__ float red[8];
  float ev[8];
  float m = -1e30f;
#pragma unroll
  for (int j = 0; j < 8; ++j) {
    ev[j] = e_ws[b * Tt + threadIdx.x + 256 * j];
    m = fmaxf(m, ev[j]);
  }
#pragma unroll
  for (int sft = 1; sft < 64; sft <<= 1) m = fmaxf(m, __shfl_xor(m, sft, 64));
  if (lane == 0) red[wv] = m;
  __syncthreads();
  m = fmaxf(fmaxf(red[0], red[1]), fmaxf(red[2], red[3]));
  float sum = 0.f;
#pragma unroll
  for (int j = 0; j < 8; ++j) { ev[j] = __expf(ev[j] - m); sum += ev[j]; }
#pragma unroll
  for (int sft = 1; sft < 64; sft <<= 1) sum += __shfl_xor(sum, sft, 64);
  if (lane == 0) red[4 + wv] = sum;
  __syncthreads();
  const float inv = 1.f / (red[4] + red[5] + red[6] + red[7]);
#pragma unroll
  for (int j = 0; j < 8; ++j) a_ws[b * Tt + threadIdx.x + 256 * j] = ev[j] * inv;
}

// ---------------- kernel 5a: partial c over 64-t chunks (deterministic) ----------------
__global__ __launch_bounds__(256) void k_c1(const float* __restrict__ h,
                                            const float* __restrict__ a_ws,
                                            float* __restrict__ cpart) {
  const int b  = blockIdx.x >> 5;
  const int tc = blockIdx.x & 31;
  const int t0 = tc << 6;
  __shared__ float a_sh[64];
  if (threadIdx.x < 64) a_sh[threadIdx.x] = a_ws[b * Tt + t0 + threadIdx.x];
  __syncthreads();
  f32x4 acc = {0.f, 0.f, 0.f, 0.f};
  const float* hb = h + ((size_t)b * Tt + t0) * Dd + threadIdx.x * 4;
#pragma unroll 4
  for (int t = 0; t < 64; ++t) {
    const f32x4 hv = *(const f32x4*)(hb + (size_t)t * Dd);
    acc += a_sh[t] * hv;
  }
  *(f32x4*)(cpart + ((size_t)(tc * 32 + b) << 10) + threadIdx.x * 4) = acc;
}

// ---------------- kernel 5b: reduce partials, store f32 ----------------
__global__ __launch_bounds__(256) void k_c2(const float* __restrict__ cpart,
                                            float* __restrict__ out) {
  const int gid = blockIdx.x * 256 + threadIdx.x;   // 0..32767
  const int b = gid >> 10;
  const int d = gid & 1023;
  float sv = 0.f;
#pragma unroll
  for (int tc = 0; tc < 32; ++tc) sv += cpart[((size_t)(tc * 32 + b) << 10) + d];
  out[gid] = sv;
}

extern "C" void kernel_launch(void* const* d_in, const int* in_sizes, int n_in,
                              void* d_out, int out_size, void* d_ws, size_t ws_size,
                              hipStream_t stream) {
  (void)in_sizes; (void)n_in; (void)out_size; (void)ws_size;
  const float* s  = (const float*)d_in[0];
  const float* h  = (const float*)d_in[1];
  const float* W  = (const float*)d_in[2];
  const float* U  = (const float*)d_in[3];
  const float* v  = (const float*)d_in[4];
  uint8_t* ws = (uint8_t*)d_ws;
  float*   w2_ws = (float*)ws;
  float*   e_ws  = (float*)(ws + WS_E);
  float*   a_ws  = (float*)(ws + WS_A);
  float*   cpart = (float*)(ws + WS_CP);
  uint8_t* U_ts  = ws + WS_UT;

  k_ws<<<128, 256, 0, stream>>>(s, W, w2_ws);
  k_ut<<<256, 256, 0, stream>>>(U, U_ts);
  k_e <<<1024, 512, 0, stream>>>(h, U_ts, w2_ws, v, e_ws);
  k_sm<<<Bb, 256, 0, stream>>>(e_ws, a_ws);
  k_c1<<<1024, 256, 0, stream>>>(h, a_ws, cpart);
  k_c2<<<128, 256, 0, stream>>>(cpart, (float*)d_out);
}